// Round 15
// baseline (47.593 us; speedup 1.0000x reference)
//
#include <hip/hip_runtime.h>
#include <cmath>

#define FDIM 128
#define NPTS 64            /* table points over d in [0, 10.24) */
#define TSTR (NPTS + 1)    /* padded col stride (uint2 units) */
#define TDLT 0.16f
#define INVTDLT 6.25f
#define CLAMPF 62.0f       /* max fidx -> idx<=62, reads idx+1<=63 */

typedef __attribute__((ext_vector_type(8))) __bf16 bf16x8;
typedef __attribute__((ext_vector_type(4))) float f32x4;

// RNE f32 -> bf16 bits
__device__ inline unsigned short f2bf(float x) {
  unsigned int u = __float_as_uint(x);
  return (unsigned short)((u + 0x7FFFu + ((u >> 16) & 1u)) >> 16);
}
__device__ inline float bfw_lo(unsigned int w) { return __uint_as_float(w << 16); }
__device__ inline float bfw_hi(unsigned int w) { return __uint_as_float(w & 0xFFFF0000u); }
__device__ inline float rdlane(float v, int j) {
  return __int_as_float(__builtin_amdgcn_readlane(__float_as_int(v), j));
}

// ---------------------------------------------------------------------------
// Table: Tq[l][pt] (uint2, col stride TSTR) where
//   .x packs bf16(S1(d_pt, f=l)),  bf16(S2(d_pt, f=l))      (lo, hi)
//   .y packs bf16(S1(d_pt, f=l+64)), bf16(S2(d_pt, f=l+64))
// with S_s(d, f) = sum_k exp(-(d - o_k)^2) * Wf[k, 3f+1+s] + bf[3f+1+s].
__global__ __launch_bounds__(128) void build_table_kernel(
    const float* __restrict__ Wf, const float* __restrict__ bf,
    unsigned int* __restrict__ Tq) {
  __shared__ float g[128];
  const int pt = blockIdx.x;
  const int tid = threadIdx.x;  // == f (0..127)
  const float dpt = pt * TDLT;
  const float o = tid * (5.0f / 127.0f);
  const float dd = dpt - o;
  g[tid] = expf(-dd * dd);
  __syncthreads();
  float s0 = bf[3 * tid + 1], s1 = bf[3 * tid + 2];
#pragma unroll 8
  for (int k = 0; k < 128; ++k) {
    s0 = fmaf(g[k], Wf[(size_t)k * 384 + 3 * tid + 1], s0);
    s1 = fmaf(g[k], Wf[(size_t)k * 384 + 3 * tid + 2], s1);
  }
  const unsigned int word = f2bf(s0) | ((unsigned int)f2bf(s1) << 16);
  Tq[((size_t)(tid & 63) * TSTR + pt) * 2 + (tid >> 6)] = word;
}

// ---------------------------------------------------------------------------
// phi = silu(h@W1+b1)@W2+b2 (used cols only), two MFMA passes, 16 rows/block,
// 4 waves, weights fragment-packed inline. Output: phiQ[row][f] u32 packing
// (phi_split1[f] lo, phi_split2[f] hi).
__global__ __launch_bounds__(256) void phi_mfma_kernel(
    const float* __restrict__ h, const float* __restrict__ W1, const float* __restrict__ b1,
    const float* __restrict__ W2, const float* __restrict__ b2,
    unsigned int* __restrict__ phiQ, int BNA) {
  __shared__ __bf16 hA[4 * 64 * 8];           // 4 KB: h tile (16 rows), A-frag layout
  __shared__ unsigned short tS[16 * 128];     // 4 KB: t tile, swizzled row-major
  const int tid = threadIdx.x;
  const int lane = tid & 63;
  const int w = tid >> 6;       // 0..3
  const int hw = lane >> 4, lcol = lane & 15;
  const int r0 = blockIdx.x * 16;

  // stage h -> A-frag bf16 (one b128 group per thread)
  {
    const int gl = tid & 63;
    const int kt = tid >> 6;
    const int row = gl & 15;
    const int k0 = kt * 32 + ((gl >> 4) << 3);
    const int gr = r0 + row;
    bf16x8 v;
    if (gr < BNA) {
      const float4 f0 = *(const float4*)&h[(size_t)gr * FDIM + k0];
      const float4 f1 = *(const float4*)&h[(size_t)gr * FDIM + k0 + 4];
      v[0] = (__bf16)f0.x; v[1] = (__bf16)f0.y; v[2] = (__bf16)f0.z; v[3] = (__bf16)f0.w;
      v[4] = (__bf16)f1.x; v[5] = (__bf16)f1.y; v[6] = (__bf16)f1.z; v[7] = (__bf16)f1.w;
    } else {
#pragma unroll
      for (int j = 0; j < 8; ++j) v[j] = (__bf16)0.0f;
    }
    *reinterpret_cast<bf16x8*>(&hA[tid * 8]) = v;
  }

  // pass1 B-frags (W1, inline pack): wave w -> f-cols [w*32, w*32+32)
  bf16x8 B1[2][4];
#pragma unroll
  for (int ftl = 0; ftl < 2; ++ftl) {
    const int col = w * 32 + ftl * 16 + lcol;
#pragma unroll
    for (int kt = 0; kt < 4; ++kt)
#pragma unroll
      for (int j = 0; j < 8; ++j)
        B1[ftl][kt][j] = (__bf16)W1[(size_t)(kt * 32 + hw * 8 + j) * FDIM + col];
  }
  float b1v[2];
#pragma unroll
  for (int ftl = 0; ftl < 2; ++ftl) b1v[ftl] = b1[w * 32 + ftl * 16 + lcol];
  __syncthreads();

  {
    bf16x8 ga[4];
#pragma unroll
    for (int kt = 0; kt < 4; ++kt)
      ga[kt] = *reinterpret_cast<const bf16x8*>(&hA[(kt * 64 + lane) * 8]);
    f32x4 acc[2];
    acc[0] = (f32x4){0.f, 0.f, 0.f, 0.f};
    acc[1] = (f32x4){0.f, 0.f, 0.f, 0.f};
#pragma unroll
    for (int ftl = 0; ftl < 2; ++ftl)
#pragma unroll
      for (int kt = 0; kt < 4; ++kt)
        acc[ftl] = __builtin_amdgcn_mfma_f32_16x16x32_bf16(ga[kt], B1[ftl][kt], acc[ftl], 0, 0, 0);
#pragma unroll
    for (int ftl = 0; ftl < 2; ++ftl)
#pragma unroll
      for (int reg = 0; reg < 4; ++reg) {
        const int row = hw * 4 + reg;
        const int fcol = w * 32 + ftl * 16 + lcol;
        const float x = acc[ftl][reg] + b1v[ftl];
        const float t = x / (1.0f + __expf(-x));
        const int byte = (row * 256 + fcol * 2) ^ ((row & 7) << 4);
        *(unsigned short*)((char*)tS + byte) = f2bf(t);
      }
  }

  // pass2 B-frags (W2 used cols, BOTH splits, inline pack)
  bf16x8 B2[2][2][4];  // [ftl][s][kt]
  float b2v[2][2];
#pragma unroll
  for (int ftl = 0; ftl < 2; ++ftl) {
    const int fcol = w * 32 + ftl * 16 + lcol;
#pragma unroll
    for (int s_ = 0; s_ < 2; ++s_) {
      const int col = 3 * fcol + 1 + s_;
#pragma unroll
      for (int kt = 0; kt < 4; ++kt)
#pragma unroll
        for (int j = 0; j < 8; ++j)
          B2[ftl][s_][kt][j] = (__bf16)W2[(size_t)(kt * 32 + hw * 8 + j) * 384 + col];
      b2v[ftl][s_] = b2[col];
    }
  }
  __syncthreads();

  {
    bf16x8 ta[4];
#pragma unroll
    for (int kt = 0; kt < 4; ++kt) {
      const int row = lcol;
      const int k0 = kt * 32 + hw * 8;
      const int byte = (row * 256 + k0 * 2) ^ ((row & 7) << 4);
      ta[kt] = *reinterpret_cast<const bf16x8*>((const char*)tS + byte);
    }
    f32x4 acc[2][2];
#pragma unroll
    for (int ftl = 0; ftl < 2; ++ftl)
#pragma unroll
      for (int s_ = 0; s_ < 2; ++s_) acc[ftl][s_] = (f32x4){0.f, 0.f, 0.f, 0.f};
#pragma unroll
    for (int ftl = 0; ftl < 2; ++ftl)
#pragma unroll
      for (int s_ = 0; s_ < 2; ++s_)
#pragma unroll
        for (int kt = 0; kt < 4; ++kt)
          acc[ftl][s_] = __builtin_amdgcn_mfma_f32_16x16x32_bf16(ta[kt], B2[ftl][s_][kt],
                                                                 acc[ftl][s_], 0, 0, 0);
#pragma unroll
    for (int ftl = 0; ftl < 2; ++ftl)
#pragma unroll
      for (int reg = 0; reg < 4; ++reg) {
        const int row = hw * 4 + reg;
        const int gr = r0 + row;
        if (gr < BNA) {
          const float v0 = acc[ftl][0][reg] + b2v[ftl][0];
          const float v1 = acc[ftl][1][reg] + b2v[ftl][1];
          const unsigned int word = f2bf(v0) | ((unsigned int)f2bf(v1) << 16);
          phiQ[(size_t)gr * FDIM + w * 32 + ftl * 16 + lcol] = word;
        }
      }
  }
}

// ---------------------------------------------------------------------------
// Main kernel (interp, software-pipelined): no MFMA, one barrier total.
// 256 threads = 4 waves, grid (ASPLIT, NC, B). Table (33 KB) in LDS -> 4
// blocks/CU. Wave covers all 256 outputs (lane l -> f=l, f=l+64, both splits)
// for its private atom chunk. Pipeline: table ds_reads for j+1 issued (via
// readlane, register-latency) before consuming j; phi prefetch 4-deep ring.
template <int ASPLIT>
__global__ __launch_bounds__(256, 4) void enc_main_kernel(
    const float* __restrict__ xyz, const float* __restrict__ cg_xyz,
    const unsigned int* __restrict__ Tg, const unsigned int* __restrict__ phiQ,
    float* __restrict__ pH, float* __restrict__ pV,
    int NA, int NC, int BNC, int BNA) {
  __shared__ unsigned int Tl[64 * TSTR * 2];  // 33.3 KB

  const int az = blockIdx.x;
  const int c = blockIdx.y;
  const int b = blockIdx.z;
  const int bc = b * NC + c;
  const int tid = threadIdx.x;
  const int l = tid & 63;
  const int wv = tid >> 6;
  const size_t arow = (size_t)b * NA;

  // load table to LDS (uint4 copies)
  {
    const uint4* src4 = (const uint4*)Tg;
    uint4* dst4 = (uint4*)Tl;
#pragma unroll
    for (int i = 0; i < 9; ++i) {
      const int idx = tid + i * 256;
      if (idx < 64 * TSTR * 2 / 4) dst4[idx] = src4[idx];
    }
  }

  const float cgx = cg_xyz[bc * 3 + 0];
  const float cgy = cg_xyz[bc * 3 + 1];
  const float cgz = cg_xyz[bc * 3 + 2];

  // atom chunk for this (az, wave)
  const int APA = (NA + ASPLIT - 1) / ASPLIT;
  const int a0 = az * APA;
  const int a_end = min(NA, a0 + APA);
  const int cnt = (a_end > a0) ? (a_end - a0) : 0;
  const int wcnt = (cnt + 3) >> 2;
  const int aw0 = a0 + wv * wcnt;
  const int aw1 = min(a_end, aw0 + wcnt);

  __syncthreads();  // table ready (only barrier)

  const int lbase = l * TSTR;  // uint2 units

  float accH0 = 0.f, accH1 = 0.f;
  float accV00 = 0.f, accV01 = 0.f, accV02 = 0.f;
  float accV10 = 0.f, accV11 = 0.f, accV12 = 0.f;

  for (int base = aw0; base < aw1; base += 64) {
    int n = aw1 - base;
    if (n > 64) n = 64;

    // batch phase: lane computes its atom's d-index + unit vector
    float fidx = 0.f, ux = 0.f, uy = 0.f, uz = 0.f;
    if (l < n) {
      const int a = base + l;
      const float dx = xyz[(arow + a) * 3 + 0] - cgx;
      const float dy = xyz[(arow + a) * 3 + 1] - cgy;
      const float dz = xyz[(arow + a) * 3 + 2] - cgz;
      const float d = sqrtf(dx * dx + dy * dy + dz * dz);
      const float inv = 1.0f / d;
      ux = dx * inv; uy = dy * inv; uz = dz * inv;
      fidx = fminf(d * INVTDLT, CLAMPF);
    }

    const unsigned int* pq = phiQ + ((size_t)(arow + base)) * FDIM + l;

    // ---- pipeline prolog ----
    float fcur = rdlane(fidx, 0);
    int idxc = (int)fcur;
    float frc = fcur - (float)idxc;
    uint2 ta = *(const uint2*)&Tl[(lbase + idxc) * 2];
    uint2 tb = *(const uint2*)&Tl[(lbase + idxc) * 2 + 2];
    unsigned int ph0a, ph0b, ph1a, ph1b, ph2a, ph2b, ph3a, ph3b;
    ph0a = (0 < n) ? pq[0] : 0u;           ph0b = (0 < n) ? pq[64] : 0u;
    ph1a = (1 < n) ? pq[1 * FDIM] : 0u;    ph1b = (1 < n) ? pq[1 * FDIM + 64] : 0u;
    ph2a = (2 < n) ? pq[2 * FDIM] : 0u;    ph2b = (2 < n) ? pq[2 * FDIM + 64] : 0u;
    ph3a = (3 < n) ? pq[3 * FDIM] : 0u;    ph3b = (3 < n) ? pq[3 * FDIM + 64] : 0u;

    for (int j = 0; j < n; ++j) {
      // ---- issue stage: table reads for j+1 (readlane is register-latency,
      // so the ds_reads get a full iteration to complete) ----
      const int j1 = (j + 1 < n) ? (j + 1) : j;
      const float fnx = rdlane(fidx, j1);
      const int idxn = (int)fnx;
      const float frn = fnx - (float)idxn;
      const uint2 tna = *(const uint2*)&Tl[(lbase + idxn) * 2];
      const uint2 tnb = *(const uint2*)&Tl[(lbase + idxn) * 2 + 2];
      // phi prefetch for j+4 (4-deep ring covers L2 latency)
      unsigned int pna = 0u, pnb = 0u;
      if (j + 4 < n) {
        pna = pq[(size_t)(j + 4) * FDIM];
        pnb = pq[(size_t)(j + 4) * FDIM + 64];
      }
      const float sux = rdlane(ux, j);
      const float suy = rdlane(uy, j);
      const float suz = rdlane(uz, j);

      // ---- consume stage: lerp table(j), fuse with phi(j) ----
      const float A1 = bfw_lo(ta.x), A2 = bfw_hi(ta.x);
      const float B1 = bfw_lo(tb.x), B2 = bfw_hi(tb.x);
      const float C1 = bfw_lo(ta.y), C2 = bfw_hi(ta.y);
      const float D1 = bfw_lo(tb.y), D2 = bfw_hi(tb.y);
      const float S1a = fmaf(frc, B1 - A1, A1);  // split1, f=l (bias baked in)
      const float S2a = fmaf(frc, B2 - A2, A2);  // split2, f=l
      const float S1b = fmaf(frc, D1 - C1, C1);  // split1, f=l+64
      const float S2b = fmaf(frc, D2 - C2, C2);  // split2, f=l+64

      const float ph1_a = bfw_lo(ph0a), ph2_a = bfw_hi(ph0a);
      const float ph1_b = bfw_lo(ph0b), ph2_b = bfw_hi(ph0b);

      accH0 = fmaf(S1a, ph1_a, accH0);
      accH1 = fmaf(S1b, ph1_b, accH1);
      const float t2a = S2a * ph2_a;
      const float t2b = S2b * ph2_b;
      accV00 = fmaf(t2a, sux, accV00);
      accV01 = fmaf(t2a, suy, accV01);
      accV02 = fmaf(t2a, suz, accV02);
      accV10 = fmaf(t2b, sux, accV10);
      accV11 = fmaf(t2b, suy, accV11);
      accV12 = fmaf(t2b, suz, accV12);

      // ---- rotate pipeline state ----
      frc = frn; ta = tna; tb = tnb;
      ph0a = ph1a; ph0b = ph1b;
      ph1a = ph2a; ph1b = ph2b;
      ph2a = ph3a; ph2b = ph3b;
      ph3a = pna;  ph3b = pnb;
    }
  }

  // write per-(az,wave) partials; lanes own distinct f -> no reduction needed
  const int p = az * 4 + wv;
  float* ph = pH + ((size_t)p * BNC + bc) * FDIM;
  ph[l] = accH0;
  ph[l + 64] = accH1;
  float* pv = pV + ((size_t)p * BNC + bc) * FDIM * 3;
  pv[l * 3 + 0] = accV00; pv[l * 3 + 1] = accV01; pv[l * 3 + 2] = accV02;
  pv[(l + 64) * 3 + 0] = accV10; pv[(l + 64) * 3 + 1] = accV11; pv[(l + 64) * 3 + 2] = accV12;
}

// ---------------------------------------------------------------------------
template <int P>
__global__ __launch_bounds__(FDIM) void reduce_kernel(
    const float* __restrict__ H, const float* __restrict__ pH, const float* __restrict__ pV,
    float* __restrict__ out, int BNC) {
  const int bc = blockIdx.x;
  const int f = threadIdx.x;
  float s = H[(size_t)bc * FDIM + f];
#pragma unroll
  for (int p = 0; p < P; ++p) s += pH[((size_t)p * BNC + bc) * FDIM + f];
  out[(size_t)bc * FDIM + f] = s;
  float* outV = out + (size_t)BNC * FDIM;
#pragma unroll
  for (int x = 0; x < 3; ++x) {
    float v = 0.f;
#pragma unroll
    for (int p = 0; p < P; ++p) v += pV[(((size_t)p * BNC + bc) * FDIM + f) * 3 + x];
    outV[((size_t)bc * FDIM + f) * 3 + x] = v;
  }
}

extern "C" void kernel_launch(void* const* d_in, const int* in_sizes, int n_in,
                              void* d_out, int out_size, void* d_ws, size_t ws_size,
                              hipStream_t stream) {
  // inputs: 0 assign(unused), 1 h, 2 H, 3 cg_xyz, 4 xyz, 5 cg_adj(unused),
  //         6 Wf, 7 bf, 8 W1, 9 b1, 10 W2, 11 b2
  const float* h      = (const float*)d_in[1];
  const float* Hc     = (const float*)d_in[2];
  const float* cg_xyz = (const float*)d_in[3];
  const float* xyz    = (const float*)d_in[4];
  const float* Wf     = (const float*)d_in[6];
  const float* bf     = (const float*)d_in[7];
  const float* W1     = (const float*)d_in[8];
  const float* b1     = (const float*)d_in[9];
  const float* W2     = (const float*)d_in[10];
  const float* b2     = (const float*)d_in[11];

  const int BNC = in_sizes[2] / FDIM;      // B*NC
  const int NC  = in_sizes[5] / BNC;       // cg_adj = B*NC*NC
  const int B   = BNC / NC;
  const int NA  = in_sizes[0] / B;
  const int BNA = B * NA;
  constexpr int ASPLIT = 8;
  constexpr int P = ASPLIT * 4;            // partials per (bc)

  // Workspace: Tq (64*TSTR*2 u32 = 33.3 KB) + phiQ (BNA*128 u32) + pH + pV
  char* wsb = (char*)d_ws;
  unsigned int* Tq   = (unsigned int*)wsb;
  unsigned int* phiQ = (unsigned int*)(wsb + 64 * TSTR * 2 * 4);
  char* pp = wsb + 64 * TSTR * 2 * 4 + (size_t)BNA * FDIM * 4;
  float* pH = (float*)pp;                  pp += (size_t)P * BNC * FDIM * 4;
  float* pV = (float*)pp;

  build_table_kernel<<<NPTS, 128, 0, stream>>>(Wf, bf, Tq);
  phi_mfma_kernel<<<(BNA + 15) / 16, 256, 0, stream>>>(h, W1, b1, W2, b2, phiQ, BNA);
  enc_main_kernel<ASPLIT><<<dim3(ASPLIT, NC, B), 256, 0, stream>>>(
      xyz, cg_xyz, Tq, phiQ, pH, pV, NA, NC, BNC, BNA);
  reduce_kernel<P><<<BNC, FDIM, 0, stream>>>(Hc, pH, pV, (float*)d_out, BNC);
}

// Round 16
// 40.290 us; speedup vs baseline: 1.1813x; 1.1813x over previous
//
#include <hip/hip_runtime.h>
#include <cmath>

#define FDIM 128
#define NPTS 64            /* table points over d in [0, 10.24) */
#define TDLT 0.16f
#define INVTDLT 6.25f
#define CLAMPF 62.0f       /* max fidx -> idx<=62, reads row idx+1<=63 */

typedef __attribute__((ext_vector_type(8))) __bf16 bf16x8;
typedef __attribute__((ext_vector_type(4))) float f32x4;

// RNE f32 -> bf16 bits
__device__ inline unsigned short f2bf(float x) {
  unsigned int u = __float_as_uint(x);
  return (unsigned short)((u + 0x7FFFu + ((u >> 16) & 1u)) >> 16);
}
__device__ inline float bfw_lo(unsigned int w) { return __uint_as_float(w << 16); }
__device__ inline float bfw_hi(unsigned int w) { return __uint_as_float(w & 0xFFFF0000u); }
__device__ inline float rdlane(float v, int j) {
  return __int_as_float(__builtin_amdgcn_readlane(__float_as_int(v), j));
}

// ---------------------------------------------------------------------------
// Table, TRANSPOSED layout: Tq[pt][l] (uint2) where
//   .x packs bf16(S1(d_pt, f=l)),   bf16(S2(d_pt, f=l))       (lo, hi)
//   .y packs bf16(S1(d_pt, f=l+64)), bf16(S2(d_pt, f=l+64))
// with S_s(d, f) = sum_k exp(-(d - o_k)^2) * Wf[k, 3f+1+s] + bf[3f+1+s].
// Row pt is 512 B; lane l reads uint2 at l*8 -> 2 lanes/bank = conflict-free.
__global__ __launch_bounds__(128) void build_table_kernel(
    const float* __restrict__ Wf, const float* __restrict__ bf,
    unsigned int* __restrict__ Tq) {
  __shared__ float g[128];
  const int pt = blockIdx.x;
  const int tid = threadIdx.x;  // == f (0..127)
  const float dpt = pt * TDLT;
  const float o = tid * (5.0f / 127.0f);
  const float dd = dpt - o;
  g[tid] = expf(-dd * dd);
  __syncthreads();
  float s0 = bf[3 * tid + 1], s1 = bf[3 * tid + 2];
#pragma unroll 8
  for (int k = 0; k < 128; ++k) {
    s0 = fmaf(g[k], Wf[(size_t)k * 384 + 3 * tid + 1], s0);
    s1 = fmaf(g[k], Wf[(size_t)k * 384 + 3 * tid + 2], s1);
  }
  const unsigned int word = f2bf(s0) | ((unsigned int)f2bf(s1) << 16);
  Tq[((size_t)pt * 64 + (tid & 63)) * 2 + (tid >> 6)] = word;
}

// ---------------------------------------------------------------------------
// phi = silu(h@W1+b1)@W2+b2 (used cols only), two MFMA passes, 16 rows/block,
// 4 waves, weights fragment-packed inline. Output: phiQ[row][f] u32 packing
// (phi_split1[f] lo, phi_split2[f] hi).
__global__ __launch_bounds__(256) void phi_mfma_kernel(
    const float* __restrict__ h, const float* __restrict__ W1, const float* __restrict__ b1,
    const float* __restrict__ W2, const float* __restrict__ b2,
    unsigned int* __restrict__ phiQ, int BNA) {
  __shared__ __bf16 hA[4 * 64 * 8];           // 4 KB: h tile (16 rows), A-frag layout
  __shared__ unsigned short tS[16 * 128];     // 4 KB: t tile, swizzled row-major
  const int tid = threadIdx.x;
  const int lane = tid & 63;
  const int w = tid >> 6;       // 0..3
  const int hw = lane >> 4, lcol = lane & 15;
  const int r0 = blockIdx.x * 16;

  // stage h -> A-frag bf16 (one b128 group per thread)
  {
    const int gl = tid & 63;
    const int kt = tid >> 6;
    const int row = gl & 15;
    const int k0 = kt * 32 + ((gl >> 4) << 3);
    const int gr = r0 + row;
    bf16x8 v;
    if (gr < BNA) {
      const float4 f0 = *(const float4*)&h[(size_t)gr * FDIM + k0];
      const float4 f1 = *(const float4*)&h[(size_t)gr * FDIM + k0 + 4];
      v[0] = (__bf16)f0.x; v[1] = (__bf16)f0.y; v[2] = (__bf16)f0.z; v[3] = (__bf16)f0.w;
      v[4] = (__bf16)f1.x; v[5] = (__bf16)f1.y; v[6] = (__bf16)f1.z; v[7] = (__bf16)f1.w;
    } else {
#pragma unroll
      for (int j = 0; j < 8; ++j) v[j] = (__bf16)0.0f;
    }
    *reinterpret_cast<bf16x8*>(&hA[tid * 8]) = v;
  }

  // pass1 B-frags (W1, inline pack): wave w -> f-cols [w*32, w*32+32)
  bf16x8 B1[2][4];
#pragma unroll
  for (int ftl = 0; ftl < 2; ++ftl) {
    const int col = w * 32 + ftl * 16 + lcol;
#pragma unroll
    for (int kt = 0; kt < 4; ++kt)
#pragma unroll
      for (int j = 0; j < 8; ++j)
        B1[ftl][kt][j] = (__bf16)W1[(size_t)(kt * 32 + hw * 8 + j) * FDIM + col];
  }
  float b1v[2];
#pragma unroll
  for (int ftl = 0; ftl < 2; ++ftl) b1v[ftl] = b1[w * 32 + ftl * 16 + lcol];
  __syncthreads();

  {
    bf16x8 ga[4];
#pragma unroll
    for (int kt = 0; kt < 4; ++kt)
      ga[kt] = *reinterpret_cast<const bf16x8*>(&hA[(kt * 64 + lane) * 8]);
    f32x4 acc[2];
    acc[0] = (f32x4){0.f, 0.f, 0.f, 0.f};
    acc[1] = (f32x4){0.f, 0.f, 0.f, 0.f};
#pragma unroll
    for (int ftl = 0; ftl < 2; ++ftl)
#pragma unroll
      for (int kt = 0; kt < 4; ++kt)
        acc[ftl] = __builtin_amdgcn_mfma_f32_16x16x32_bf16(ga[kt], B1[ftl][kt], acc[ftl], 0, 0, 0);
#pragma unroll
    for (int ftl = 0; ftl < 2; ++ftl)
#pragma unroll
      for (int reg = 0; reg < 4; ++reg) {
        const int row = hw * 4 + reg;
        const int fcol = w * 32 + ftl * 16 + lcol;
        const float x = acc[ftl][reg] + b1v[ftl];
        const float t = x / (1.0f + __expf(-x));
        const int byte = (row * 256 + fcol * 2) ^ ((row & 7) << 4);
        *(unsigned short*)((char*)tS + byte) = f2bf(t);
      }
  }

  // pass2 B-frags (W2 used cols, BOTH splits, inline pack)
  bf16x8 B2[2][2][4];  // [ftl][s][kt]
  float b2v[2][2];
#pragma unroll
  for (int ftl = 0; ftl < 2; ++ftl) {
    const int fcol = w * 32 + ftl * 16 + lcol;
#pragma unroll
    for (int s_ = 0; s_ < 2; ++s_) {
      const int col = 3 * fcol + 1 + s_;
#pragma unroll
      for (int kt = 0; kt < 4; ++kt)
#pragma unroll
        for (int j = 0; j < 8; ++j)
          B2[ftl][s_][kt][j] = (__bf16)W2[(size_t)(kt * 32 + hw * 8 + j) * 384 + col];
      b2v[ftl][s_] = b2[col];
    }
  }
  __syncthreads();

  {
    bf16x8 ta[4];
#pragma unroll
    for (int kt = 0; kt < 4; ++kt) {
      const int row = lcol;
      const int k0 = kt * 32 + hw * 8;
      const int byte = (row * 256 + k0 * 2) ^ ((row & 7) << 4);
      ta[kt] = *reinterpret_cast<const bf16x8*>((const char*)tS + byte);
    }
    f32x4 acc[2][2];
#pragma unroll
    for (int ftl = 0; ftl < 2; ++ftl)
#pragma unroll
      for (int s_ = 0; s_ < 2; ++s_) acc[ftl][s_] = (f32x4){0.f, 0.f, 0.f, 0.f};
#pragma unroll
    for (int ftl = 0; ftl < 2; ++ftl)
#pragma unroll
      for (int s_ = 0; s_ < 2; ++s_)
#pragma unroll
        for (int kt = 0; kt < 4; ++kt)
          acc[ftl][s_] = __builtin_amdgcn_mfma_f32_16x16x32_bf16(ta[kt], B2[ftl][s_][kt],
                                                                 acc[ftl][s_], 0, 0, 0);
#pragma unroll
    for (int ftl = 0; ftl < 2; ++ftl)
#pragma unroll
      for (int reg = 0; reg < 4; ++reg) {
        const int row = hw * 4 + reg;
        const int gr = r0 + row;
        if (gr < BNA) {
          const float v0 = acc[ftl][0][reg] + b2v[ftl][0];
          const float v1 = acc[ftl][1][reg] + b2v[ftl][1];
          const unsigned int word = f2bf(v0) | ((unsigned int)f2bf(v1) << 16);
          phiQ[(size_t)gr * FDIM + w * 32 + ftl * 16 + lcol] = word;
        }
      }
  }
}

// ---------------------------------------------------------------------------
// Main kernel (interp, 4-wide): no MFMA, one barrier. 256 threads = 4 waves,
// grid (ASPLIT, NC, B). Transposed table (32 KB) in LDS -> conflict-free
// ds_read_b64 (lane l at l*8, wave-uniform row) and 4 blocks/CU. Wave covers
// all 256 outputs (lane l -> f=l, f=l+64, both splits) for its private atom
// chunk. 4 atoms processed per group: 8 ds_reads + 8 phi loads issued
// together (MLP=4x) before the consume stage.
template <int ASPLIT>
__global__ __launch_bounds__(256, 4) void enc_main_kernel(
    const float* __restrict__ xyz, const float* __restrict__ cg_xyz,
    const unsigned int* __restrict__ Tg, const unsigned int* __restrict__ phiQ,
    float* __restrict__ pH, float* __restrict__ pV,
    int NA, int NC, int BNC, int BNA) {
  __shared__ uint2 Tl[NPTS * 64];  // 32 KB, [pt][l]

  const int az = blockIdx.x;
  const int c = blockIdx.y;
  const int b = blockIdx.z;
  const int bc = b * NC + c;
  const int tid = threadIdx.x;
  const int l = tid & 63;
  const int wv = tid >> 6;
  const size_t arow = (size_t)b * NA;

  // load table to LDS (exactly 8 uint4 per thread)
  {
    const uint4* src4 = (const uint4*)Tg;
    uint4* dst4 = (uint4*)Tl;
#pragma unroll
    for (int i = 0; i < 8; ++i) dst4[tid + i * 256] = src4[tid + i * 256];
  }

  const float cgx = cg_xyz[bc * 3 + 0];
  const float cgy = cg_xyz[bc * 3 + 1];
  const float cgz = cg_xyz[bc * 3 + 2];

  // atom chunk for this (az, wave)
  const int APA = (NA + ASPLIT - 1) / ASPLIT;
  const int a0 = az * APA;
  const int a_end = min(NA, a0 + APA);
  const int cnt = (a_end > a0) ? (a_end - a0) : 0;
  const int wcnt = (cnt + 3) >> 2;
  const int aw0 = a0 + wv * wcnt;
  const int aw1 = min(a_end, aw0 + wcnt);

  __syncthreads();  // table ready (only barrier)

  float accH0 = 0.f, accH1 = 0.f;
  float accV00 = 0.f, accV01 = 0.f, accV02 = 0.f;
  float accV10 = 0.f, accV11 = 0.f, accV12 = 0.f;

  for (int base = aw0; base < aw1; base += 64) {
    int n = aw1 - base;
    if (n > 64) n = 64;

    // batch phase: lane computes its atom's d-index + unit vector
    float fidx = 0.f, ux = 0.f, uy = 0.f, uz = 0.f;
    if (l < n) {
      const int a = base + l;
      const float dx = xyz[(arow + a) * 3 + 0] - cgx;
      const float dy = xyz[(arow + a) * 3 + 1] - cgy;
      const float dz = xyz[(arow + a) * 3 + 2] - cgz;
      const float d = sqrtf(dx * dx + dy * dy + dz * dz);
      const float inv = 1.0f / d;
      ux = dx * inv; uy = dy * inv; uz = dz * inv;
      fidx = fminf(d * INVTDLT, CLAMPF);
    }

    const unsigned int* pq = phiQ + ((size_t)(arow + base)) * FDIM + l;

    for (int jb = 0; jb < n; jb += 4) {
      // ---- issue stage: 4 atoms' table reads + phi loads together ----
      uint2 t0[4], t1[4];
      float fr[4], sux[4], suy[4], suz[4];
      unsigned int pa[4], pb[4];
#pragma unroll
      for (int q = 0; q < 4; ++q) {
        const int jj = jb + q;               // wave-uniform
        const int jl = jj & 63;              // valid lane (jj <= 66 never: n<=64 so jj<=63+3? guard below)
        const float sf = rdlane(fidx, jl);
        const int idx = (int)sf;
        fr[q] = sf - (float)idx;
        t0[q] = Tl[idx * 64 + l];
        t1[q] = Tl[idx * 64 + 64 + l];
        sux[q] = rdlane(ux, jl);
        suy[q] = rdlane(uy, jl);
        suz[q] = rdlane(uz, jl);
        if (jj < n) {
          pa[q] = pq[(size_t)jj * FDIM];
          pb[q] = pq[(size_t)jj * FDIM + 64];
        } else {
          pa[q] = 0u; pb[q] = 0u;            // zero phi -> zero contribution
        }
      }
      // ---- consume stage: 4 atoms ----
#pragma unroll
      for (int q = 0; q < 4; ++q) {
        const float A1 = bfw_lo(t0[q].x), A2 = bfw_hi(t0[q].x);
        const float B1 = bfw_lo(t1[q].x), B2 = bfw_hi(t1[q].x);
        const float C1 = bfw_lo(t0[q].y), C2 = bfw_hi(t0[q].y);
        const float D1 = bfw_lo(t1[q].y), D2 = bfw_hi(t1[q].y);
        const float S1a = fmaf(fr[q], B1 - A1, A1);  // split1, f=l (bias baked in)
        const float S2a = fmaf(fr[q], B2 - A2, A2);  // split2, f=l
        const float S1b = fmaf(fr[q], D1 - C1, C1);  // split1, f=l+64
        const float S2b = fmaf(fr[q], D2 - C2, C2);  // split2, f=l+64

        const float p1a = bfw_lo(pa[q]), p2a = bfw_hi(pa[q]);
        const float p1b = bfw_lo(pb[q]), p2b = bfw_hi(pb[q]);

        accH0 = fmaf(S1a, p1a, accH0);
        accH1 = fmaf(S1b, p1b, accH1);
        const float t2a = S2a * p2a;
        const float t2b = S2b * p2b;
        accV00 = fmaf(t2a, sux[q], accV00);
        accV01 = fmaf(t2a, suy[q], accV01);
        accV02 = fmaf(t2a, suz[q], accV02);
        accV10 = fmaf(t2b, sux[q], accV10);
        accV11 = fmaf(t2b, suy[q], accV11);
        accV12 = fmaf(t2b, suz[q], accV12);
      }
    }
  }

  // write per-(az,wave) partials; lanes own distinct f -> no reduction needed
  const int p = az * 4 + wv;
  float* ph = pH + ((size_t)p * BNC + bc) * FDIM;
  ph[l] = accH0;
  ph[l + 64] = accH1;
  float* pv = pV + ((size_t)p * BNC + bc) * FDIM * 3;
  pv[l * 3 + 0] = accV00; pv[l * 3 + 1] = accV01; pv[l * 3 + 2] = accV02;
  pv[(l + 64) * 3 + 0] = accV10; pv[(l + 64) * 3 + 1] = accV11; pv[(l + 64) * 3 + 2] = accV12;
}

// ---------------------------------------------------------------------------
template <int P>
__global__ __launch_bounds__(FDIM) void reduce_kernel(
    const float* __restrict__ H, const float* __restrict__ pH, const float* __restrict__ pV,
    float* __restrict__ out, int BNC) {
  const int bc = blockIdx.x;
  const int f = threadIdx.x;
  float s = H[(size_t)bc * FDIM + f];
#pragma unroll
  for (int p = 0; p < P; ++p) s += pH[((size_t)p * BNC + bc) * FDIM + f];
  out[(size_t)bc * FDIM + f] = s;
  float* outV = out + (size_t)BNC * FDIM;
#pragma unroll
  for (int x = 0; x < 3; ++x) {
    float v = 0.f;
#pragma unroll
    for (int p = 0; p < P; ++p) v += pV[(((size_t)p * BNC + bc) * FDIM + f) * 3 + x];
    outV[((size_t)bc * FDIM + f) * 3 + x] = v;
  }
}

extern "C" void kernel_launch(void* const* d_in, const int* in_sizes, int n_in,
                              void* d_out, int out_size, void* d_ws, size_t ws_size,
                              hipStream_t stream) {
  // inputs: 0 assign(unused), 1 h, 2 H, 3 cg_xyz, 4 xyz, 5 cg_adj(unused),
  //         6 Wf, 7 bf, 8 W1, 9 b1, 10 W2, 11 b2
  const float* h      = (const float*)d_in[1];
  const float* Hc     = (const float*)d_in[2];
  const float* cg_xyz = (const float*)d_in[3];
  const float* xyz    = (const float*)d_in[4];
  const float* Wf     = (const float*)d_in[6];
  const float* bf     = (const float*)d_in[7];
  const float* W1     = (const float*)d_in[8];
  const float* b1     = (const float*)d_in[9];
  const float* W2     = (const float*)d_in[10];
  const float* b2     = (const float*)d_in[11];

  const int BNC = in_sizes[2] / FDIM;      // B*NC
  const int NC  = in_sizes[5] / BNC;       // cg_adj = B*NC*NC
  const int B   = BNC / NC;
  const int NA  = in_sizes[0] / B;
  const int BNA = B * NA;
  constexpr int ASPLIT = 8;
  constexpr int P = ASPLIT * 4;            // partials per (bc)

  // Workspace: Tq (64*64 uint2 = 32 KB) + phiQ (BNA*128 u32) + pH + pV
  char* wsb = (char*)d_ws;
  unsigned int* Tq   = (unsigned int*)wsb;
  unsigned int* phiQ = (unsigned int*)(wsb + 64 * 64 * 8);
  char* pp = wsb + 64 * 64 * 8 + (size_t)BNA * FDIM * 4;
  float* pH = (float*)pp;                  pp += (size_t)P * BNC * FDIM * 4;
  float* pV = (float*)pp;

  build_table_kernel<<<NPTS, 128, 0, stream>>>(Wf, bf, Tq);
  phi_mfma_kernel<<<(BNA + 15) / 16, 256, 0, stream>>>(h, W1, b1, W2, b2, phiQ, BNA);
  enc_main_kernel<ASPLIT><<<dim3(ASPLIT, NC, B), 256, 0, stream>>>(
      xyz, cg_xyz, Tq, phiQ, pH, pV, NA, NC, BNC, BNA);
  reduce_kernel<P><<<BNC, FDIM, 0, stream>>>(Hc, pH, pV, (float*)d_out, BNC);
}